// Round 3
// baseline (901.455 us; speedup 1.0000x reference)
//
#include <hip/hip_runtime.h>
#include <hip/hip_bf16.h>
#include <math.h>

#define NN 50000
#define EE 800000
// QD = 128, PD = 64, H = 8, HD = 16, H*HD = 128

// ---------------- GEMM: C[n,j] = (sum_k A[n,k]*W[k,j]) * scale + bias[j] ----
// Block = 256 threads, 64 rows/block, full 128-col width.
// A tile staged in LDS (stride 132 to break bank conflicts), W streamed from
// global (64KB, L1/L2 resident, coalesced float4 per k-step).
__global__ __launch_bounds__(256) void gemm128_k(
    const float* __restrict__ A, const float* __restrict__ W,
    const float* __restrict__ bias, float* __restrict__ C,
    int n_rows, float scale) {
  __shared__ float Al[64 * 132];
  const int t = threadIdx.x;
  const int row0 = blockIdx.x * 64;
  for (int i = t; i < 64 * 32; i += 256) {
    int r = i >> 5, c4 = i & 31;
    int gr = row0 + r;
    float4 val = make_float4(0.f, 0.f, 0.f, 0.f);
    if (gr < n_rows) val = *(const float4*)&A[(size_t)gr * 128 + c4 * 4];
    *(float4*)&Al[r * 132 + c4 * 4] = val;
  }
  __syncthreads();
  const int tx = t & 31;   // cols tx*4 .. tx*4+3
  const int ty = t >> 5;   // rows ty*8 .. ty*8+7
  float acc[8][4] = {};
  #pragma unroll 8
  for (int k = 0; k < 128; ++k) {
    float4 w = *(const float4*)&W[k * 128 + tx * 4];
    #pragma unroll
    for (int r = 0; r < 8; ++r) {
      float a = Al[(ty * 8 + r) * 132 + k];
      acc[r][0] = fmaf(a, w.x, acc[r][0]);
      acc[r][1] = fmaf(a, w.y, acc[r][1]);
      acc[r][2] = fmaf(a, w.z, acc[r][2]);
      acc[r][3] = fmaf(a, w.w, acc[r][3]);
    }
  }
  float4 bv = make_float4(0.f, 0.f, 0.f, 0.f);
  if (bias) bv = *(const float4*)&bias[tx * 4];
  #pragma unroll
  for (int r = 0; r < 8; ++r) {
    int gr = row0 + ty * 8 + r;
    if (gr < n_rows) {
      float4 o;
      o.x = acc[r][0] * scale + bv.x;
      o.y = acc[r][1] * scale + bv.y;
      o.z = acc[r][2] * scale + bv.z;
      o.w = acc[r][3] * scale + bv.w;
      *(float4*)&C[(size_t)gr * 128 + tx * 4] = o;
    }
  }
}

// ---------------- edge attention logits -------------------------------------
// thread -> (edge, head); 8 lanes per edge. attn[e,h] = qh[dst,h,:].kh[src,h,:]
//                                                      + edges[e,:]@Wb[:,h] + bb[h]
__global__ __launch_bounds__(256) void edge_attn_k(
    const float* __restrict__ qh, const float* __restrict__ kh,
    const float* __restrict__ edges, const float* __restrict__ Wb,
    const float* __restrict__ bb, const int* __restrict__ eidx,
    float* __restrict__ attn) {
  __shared__ float Wbl[64 * 8];
  __shared__ float bbl[8];
  for (int i = threadIdx.x; i < 64 * 8; i += 256) Wbl[i] = Wb[i];
  if (threadIdx.x < 8) bbl[threadIdx.x] = bb[threadIdx.x];
  __syncthreads();
  int gid = blockIdx.x * 256 + threadIdx.x;
  int e = gid >> 3, h = gid & 7;
  if (e >= EE) return;
  int dst = eidx[2 * e + 0];
  int src = eidx[2 * e + 1];
  const float4* qv = (const float4*)&qh[(size_t)dst * 128 + h * 16];
  const float4* kv = (const float4*)&kh[(size_t)src * 128 + h * 16];
  float s = 0.f;
  #pragma unroll
  for (int i = 0; i < 4; ++i) {
    float4 a = qv[i], b = kv[i];
    s = fmaf(a.x, b.x, s); s = fmaf(a.y, b.y, s);
    s = fmaf(a.z, b.z, s); s = fmaf(a.w, b.w, s);
  }
  const float4* ev = (const float4*)&edges[(size_t)e * 64];
  float bsum = bbl[h];
  #pragma unroll
  for (int p4 = 0; p4 < 16; ++p4) {
    float4 ee = ev[p4];
    bsum = fmaf(ee.x, Wbl[(p4 * 4 + 0) * 8 + h], bsum);
    bsum = fmaf(ee.y, Wbl[(p4 * 4 + 1) * 8 + h], bsum);
    bsum = fmaf(ee.z, Wbl[(p4 * 4 + 2) * 8 + h], bsum);
    bsum = fmaf(ee.w, Wbl[(p4 * 4 + 3) * 8 + h], bsum);
  }
  attn[(size_t)e * 8 + h] = s + bsum;
}

// ---------------- CSR build -------------------------------------------------
__global__ __launch_bounds__(256) void count_k(const int* __restrict__ eidx,
                                               int* __restrict__ counts) {
  int e = blockIdx.x * 256 + threadIdx.x;
  if (e < EE) atomicAdd(&counts[eidx[2 * e]], 1);
}

__global__ __launch_bounds__(1024) void scan_k(const int* __restrict__ counts,
                                               int* __restrict__ offs,
                                               int* __restrict__ cursor) {
  __shared__ int sd[1024];
  int t = threadIdx.x;
  int carry = 0;
  for (int base = 0; base < NN; base += 1024) {
    int idx = base + t;
    int val = (idx < NN) ? counts[idx] : 0;
    sd[t] = val;
    __syncthreads();
    for (int off = 1; off < 1024; off <<= 1) {
      int x = (t >= off) ? sd[t - off] : 0;
      __syncthreads();
      sd[t] += x;
      __syncthreads();
    }
    int excl = carry + sd[t] - val;
    if (idx < NN) { offs[idx] = excl; cursor[idx] = excl; }
    carry += sd[1023];
    __syncthreads();
  }
  if (t == 0) offs[NN] = carry;
}

__global__ __launch_bounds__(256) void scatter_k(const int* __restrict__ eidx,
                                                 int* __restrict__ cursor,
                                                 int* __restrict__ elist) {
  int e = blockIdx.x * 256 + threadIdx.x;
  if (e < EE) {
    int pos = atomicAdd(&cursor[eidx[2 * e]], 1);
    elist[pos] = e;
  }
}

// ---------------- per-node softmax + PV aggregation -------------------------
// One wave per node. lane owns dims d = 2*lane, 2*lane+1; head = lane/8.
// Loop 1: per-head max. Loop 2: den += exp, acc += exp*vh[src]. Store acc/den.
__global__ __launch_bounds__(256) void aggregate_k(
    const float* __restrict__ attn, const float* __restrict__ vh,
    const int* __restrict__ eidx, const int* __restrict__ offs,
    const int* __restrict__ elist, float* __restrict__ o) {
  int wid = (blockIdx.x * 256 + threadIdx.x) >> 6;  // node id
  int lane = threadIdx.x & 63;
  if (wid >= NN) return;
  int beg = offs[wid], end = offs[wid + 1];
  int h = lane >> 3;        // = (2*lane)/16
  int d = lane * 2;
  float m = -INFINITY;
  for (int i = beg; i < end; ++i) {
    int e = elist[i];
    m = fmaxf(m, attn[(size_t)e * 8 + h]);
  }
  float den = 0.f, acc0 = 0.f, acc1 = 0.f;
  for (int i = beg; i < end; ++i) {
    int e = elist[i];
    float a = attn[(size_t)e * 8 + h];
    int src = eidx[2 * e + 1];
    float ex = __expf(a - m);
    den += ex;
    float2 vv = *(const float2*)&vh[(size_t)src * 128 + d];
    acc0 = fmaf(ex, vv.x, acc0);
    acc1 = fmaf(ex, vv.y, acc1);
  }
  float2 r;
  if (end > beg) { r.x = acc0 / den; r.y = acc1 / den; }
  else           { r.x = 0.f; r.y = 0.f; }
  *(float2*)&o[(size_t)wid * 128 + d] = r;
}

// ---------------- launch ----------------------------------------------------
extern "C" void kernel_launch(void* const* d_in, const int* in_sizes, int n_in,
                              void* d_out, int out_size, void* d_ws, size_t ws_size,
                              hipStream_t stream) {
  const float* q     = (const float*)d_in[0];
  const float* k     = (const float*)d_in[1];
  const float* v     = (const float*)d_in[2];
  const float* edges = (const float*)d_in[3];
  const int*   eidx  = (const int*)  d_in[4];
  const float* Wq    = (const float*)d_in[5];
  const float* Wk    = (const float*)d_in[6];
  const float* Wv    = (const float*)d_in[7];
  const float* Wo    = (const float*)d_in[8];
  const float* bo    = (const float*)d_in[9];
  const float* Wb    = (const float*)d_in[10];
  const float* bb    = (const float*)d_in[11];
  float* out = (float*)d_out;

  char* ws = (char*)d_ws;
  float* qh   = (float*)ws; ws += (size_t)NN * 128 * 4;   // also reused as o-buffer
  float* kh   = (float*)ws; ws += (size_t)NN * 128 * 4;
  float* vh   = (float*)ws; ws += (size_t)NN * 128 * 4;
  float* attn = (float*)ws; ws += (size_t)EE * 8 * 4;
  int* counts = (int*)ws;   ws += (size_t)NN * 4;
  int* offs   = (int*)ws;   ws += (size_t)(NN + 1) * 4;
  int* cursor = (int*)ws;   ws += (size_t)NN * 4;
  int* elist  = (int*)ws;   ws += (size_t)EE * 4;
  float* obuf = qh;  // qh dead after edge_attn_k

  hipMemsetAsync(counts, 0, (size_t)NN * 4, stream);

  const int gemm_grid = (NN + 63) / 64;  // 782
  gemm128_k<<<gemm_grid, 256, 0, stream>>>(q, Wq, nullptr, qh, NN, 0.25f); // HD^-0.5
  gemm128_k<<<gemm_grid, 256, 0, stream>>>(k, Wk, nullptr, kh, NN, 1.0f);
  gemm128_k<<<gemm_grid, 256, 0, stream>>>(v, Wv, nullptr, vh, NN, 1.0f);

  count_k  <<<(EE + 255) / 256, 256, 0, stream>>>(eidx, counts);
  scan_k   <<<1, 1024, 0, stream>>>(counts, offs, cursor);
  scatter_k<<<(EE + 255) / 256, 256, 0, stream>>>(eidx, cursor, elist);

  edge_attn_k<<<(EE * 8 + 255) / 256, 256, 0, stream>>>(qh, kh, edges, Wb, bb, eidx, attn);

  aggregate_k<<<(NN * 64 + 255) / 256, 256, 0, stream>>>(attn, vh, eidx, offs, elist, obuf);

  gemm128_k<<<gemm_grid, 256, 0, stream>>>(obuf, Wo, bo, out, NN, 1.0f);
}

// Round 4
// 762.190 us; speedup vs baseline: 1.1827x; 1.1827x over previous
//
#include <hip/hip_runtime.h>
#include <hip/hip_bf16.h>
#include <math.h>

#define NN 50000
#define EE 800000
#define NBLK 49  // ceil(NN/1024)
// QD = 128, PD = 64, H = 8, HD = 16, H*HD = 128

// ---------------- GEMM: C[n,j] = (sum_k A[n,k]*W[k,j]) * scale + bias[j] ----
__global__ __launch_bounds__(256) void gemm128_k(
    const float* __restrict__ A, const float* __restrict__ W,
    const float* __restrict__ bias, float* __restrict__ C,
    int n_rows, float scale) {
  __shared__ float Al[64 * 132];
  const int t = threadIdx.x;
  const int row0 = blockIdx.x * 64;
  for (int i = t; i < 64 * 32; i += 256) {
    int r = i >> 5, c4 = i & 31;
    int gr = row0 + r;
    float4 val = make_float4(0.f, 0.f, 0.f, 0.f);
    if (gr < n_rows) val = *(const float4*)&A[(size_t)gr * 128 + c4 * 4];
    *(float4*)&Al[r * 132 + c4 * 4] = val;
  }
  __syncthreads();
  const int tx = t & 31;   // cols tx*4 .. tx*4+3
  const int ty = t >> 5;   // rows ty*8 .. ty*8+7
  float acc[8][4] = {};
  #pragma unroll 8
  for (int k = 0; k < 128; ++k) {
    float4 w = *(const float4*)&W[k * 128 + tx * 4];
    #pragma unroll
    for (int r = 0; r < 8; ++r) {
      float a = Al[(ty * 8 + r) * 132 + k];
      acc[r][0] = fmaf(a, w.x, acc[r][0]);
      acc[r][1] = fmaf(a, w.y, acc[r][1]);
      acc[r][2] = fmaf(a, w.z, acc[r][2]);
      acc[r][3] = fmaf(a, w.w, acc[r][3]);
    }
  }
  float4 bv = make_float4(0.f, 0.f, 0.f, 0.f);
  if (bias) bv = *(const float4*)&bias[tx * 4];
  #pragma unroll
  for (int r = 0; r < 8; ++r) {
    int gr = row0 + ty * 8 + r;
    if (gr < n_rows) {
      float4 o;
      o.x = acc[r][0] * scale + bv.x;
      o.y = acc[r][1] * scale + bv.y;
      o.z = acc[r][2] * scale + bv.z;
      o.w = acc[r][3] * scale + bv.w;
      *(float4*)&C[(size_t)gr * 128 + tx * 4] = o;
    }
  }
}

// ---------------- CSR build -------------------------------------------------
__global__ __launch_bounds__(256) void count_k(const int* __restrict__ eidx,
                                               int* __restrict__ counts) {
  int e = blockIdx.x * 256 + threadIdx.x;
  if (e < EE) atomicAdd(&counts[eidx[2 * e]], 1);
}

// 49 blocks: partials[b] = sum counts[b*1024 .. b*1024+1023]
__global__ __launch_bounds__(256) void partial_k(const int* __restrict__ counts,
                                                 int* __restrict__ partials) {
  __shared__ int sd[256];
  int b = blockIdx.x, t = threadIdx.x;
  int sum = 0;
  for (int i = t; i < 1024; i += 256) {
    int idx = b * 1024 + i;
    sum += (idx < NN) ? counts[idx] : 0;
  }
  sd[t] = sum;
  __syncthreads();
  for (int off = 128; off > 0; off >>= 1) {
    if (t < off) sd[t] += sd[t + off];
    __syncthreads();
  }
  if (t == 0) partials[b] = sd[0];
}

// 49 blocks x 1024: offs[idx] = sum(partials[0..b-1]) + exclusive_scan_in_block
__global__ __launch_bounds__(1024) void offs_k(const int* __restrict__ counts,
                                               const int* __restrict__ partials,
                                               int* __restrict__ offs,
                                               int* __restrict__ cursor) {
  __shared__ int sd[1024];
  int b = blockIdx.x, t = threadIdx.x;
  int idx = b * 1024 + t;
  int val = (idx < NN) ? counts[idx] : 0;
  sd[t] = val;
  __syncthreads();
  for (int off = 1; off < 1024; off <<= 1) {
    int x = (t >= off) ? sd[t - off] : 0;
    __syncthreads();
    sd[t] += x;
    __syncthreads();
  }
  int base = 0;
  for (int j = 0; j < b; ++j) base += partials[j];  // uniform scalar loads, <=48
  int excl = base + sd[t] - val;
  if (idx < NN) { offs[idx] = excl; cursor[idx] = excl; }
  if (b == 0 && t == 0) {
    int tot = 0;
    for (int j = 0; j < NBLK; ++j) tot += partials[j];
    offs[NN] = tot;
  }
}

// scatter: CSR slot for each edge + permuted dst/src streams
__global__ __launch_bounds__(256) void scatter_k(const int* __restrict__ eidx,
                                                 int* __restrict__ cursor,
                                                 int* __restrict__ elist,
                                                 int* __restrict__ dstp,
                                                 int* __restrict__ srcp) {
  int e = blockIdx.x * 256 + threadIdx.x;
  if (e < EE) {
    int dst = eidx[2 * e + 0];
    int src = eidx[2 * e + 1];
    int pos = atomicAdd(&cursor[dst], 1);
    elist[pos] = e;
    dstp[pos] = dst;
    srcp[pos] = src;
  }
}

// ---------------- edge attention logits (CSR order) -------------------------
// thread -> (pos, head); 8 lanes per slot. Writes attnp[pos,h] STREAMING.
// Consecutive pos share dst -> qh reads are L1-local. edges rows gathered once.
__global__ __launch_bounds__(256) void edge_attn_k(
    const float* __restrict__ qh, const float* __restrict__ kh,
    const float* __restrict__ edges, const float* __restrict__ Wb,
    const float* __restrict__ bb, const int* __restrict__ elist,
    const int* __restrict__ dstp, const int* __restrict__ srcp,
    float* __restrict__ attnp) {
  __shared__ float Wbl[64 * 8];
  __shared__ float bbl[8];
  for (int i = threadIdx.x; i < 64 * 8; i += 256) Wbl[i] = Wb[i];
  if (threadIdx.x < 8) bbl[threadIdx.x] = bb[threadIdx.x];
  __syncthreads();
  int gid = blockIdx.x * 256 + threadIdx.x;
  int pos = gid >> 3, h = gid & 7;
  if (pos >= EE) return;
  int e   = elist[pos];
  int dst = dstp[pos];
  int src = srcp[pos];
  const float4* qv = (const float4*)&qh[(size_t)dst * 128 + h * 16];
  const float4* kv = (const float4*)&kh[(size_t)src * 128 + h * 16];
  float s = 0.f;
  #pragma unroll
  for (int i = 0; i < 4; ++i) {
    float4 a = qv[i], b = kv[i];
    s = fmaf(a.x, b.x, s); s = fmaf(a.y, b.y, s);
    s = fmaf(a.z, b.z, s); s = fmaf(a.w, b.w, s);
  }
  const float4* ev = (const float4*)&edges[(size_t)e * 64];
  float bsum = bbl[h];
  #pragma unroll
  for (int p4 = 0; p4 < 16; ++p4) {
    float4 ee = ev[p4];
    bsum = fmaf(ee.x, Wbl[(p4 * 4 + 0) * 8 + h], bsum);
    bsum = fmaf(ee.y, Wbl[(p4 * 4 + 1) * 8 + h], bsum);
    bsum = fmaf(ee.z, Wbl[(p4 * 4 + 2) * 8 + h], bsum);
    bsum = fmaf(ee.w, Wbl[(p4 * 4 + 3) * 8 + h], bsum);
  }
  attnp[(size_t)pos * 8 + h] = s + bsum;
}

// ---------------- per-node softmax + PV aggregation (contiguous) ------------
// One wave per node; lane owns dims d=2*lane,2*lane+1; h=lane/8.
// attnp/srcp reads are contiguous in i -> no dependent chain; only vh gathers.
__global__ __launch_bounds__(256) void aggregate_k(
    const float* __restrict__ attnp, const float* __restrict__ vh,
    const int* __restrict__ srcp, const int* __restrict__ offs,
    float* __restrict__ o) {
  int wid = (blockIdx.x * 256 + threadIdx.x) >> 6;  // node id
  int lane = threadIdx.x & 63;
  if (wid >= NN) return;
  int beg = offs[wid], end = offs[wid + 1];
  int h = lane >> 3;
  int d = lane * 2;
  float m = -INFINITY;
  for (int i = beg; i < end; ++i)
    m = fmaxf(m, attnp[(size_t)i * 8 + h]);
  float den = 0.f, acc0 = 0.f, acc1 = 0.f;
  for (int i = beg; i < end; ++i) {
    float a = attnp[(size_t)i * 8 + h];
    int src = srcp[i];
    float ex = __expf(a - m);
    den += ex;
    float2 vv = *(const float2*)&vh[(size_t)src * 128 + d];
    acc0 = fmaf(ex, vv.x, acc0);
    acc1 = fmaf(ex, vv.y, acc1);
  }
  float2 r;
  if (end > beg) { r.x = acc0 / den; r.y = acc1 / den; }
  else           { r.x = 0.f; r.y = 0.f; }
  *(float2*)&o[(size_t)wid * 128 + d] = r;
}

// ---------------- launch ----------------------------------------------------
extern "C" void kernel_launch(void* const* d_in, const int* in_sizes, int n_in,
                              void* d_out, int out_size, void* d_ws, size_t ws_size,
                              hipStream_t stream) {
  const float* q     = (const float*)d_in[0];
  const float* k     = (const float*)d_in[1];
  const float* v     = (const float*)d_in[2];
  const float* edges = (const float*)d_in[3];
  const int*   eidx  = (const int*)  d_in[4];
  const float* Wq    = (const float*)d_in[5];
  const float* Wk    = (const float*)d_in[6];
  const float* Wv    = (const float*)d_in[7];
  const float* Wo    = (const float*)d_in[8];
  const float* bo    = (const float*)d_in[9];
  const float* Wb    = (const float*)d_in[10];
  const float* bb    = (const float*)d_in[11];
  float* out = (float*)d_out;

  char* ws = (char*)d_ws;
  float* qh    = (float*)ws; ws += (size_t)NN * 128 * 4;   // reused as o-buffer
  float* kh    = (float*)ws; ws += (size_t)NN * 128 * 4;
  float* vh    = (float*)ws; ws += (size_t)NN * 128 * 4;
  float* attnp = (float*)ws; ws += (size_t)EE * 8 * 4;
  int* counts  = (int*)ws;   ws += (size_t)NN * 4;
  int* offs    = (int*)ws;   ws += (size_t)(NN + 1) * 4;
  int* cursor  = (int*)ws;   ws += (size_t)NN * 4;
  int* partials= (int*)ws;   ws += (size_t)64 * 4;
  int* elist   = (int*)ws;   ws += (size_t)EE * 4;
  int* dstp    = (int*)ws;   ws += (size_t)EE * 4;
  int* srcp    = (int*)ws;   ws += (size_t)EE * 4;
  float* obuf = qh;  // qh dead after edge_attn_k

  hipMemsetAsync(counts, 0, (size_t)NN * 4, stream);

  const int gemm_grid = (NN + 63) / 64;  // 782
  gemm128_k<<<gemm_grid, 256, 0, stream>>>(q, Wq, nullptr, qh, NN, 0.25f); // HD^-0.5
  gemm128_k<<<gemm_grid, 256, 0, stream>>>(k, Wk, nullptr, kh, NN, 1.0f);
  gemm128_k<<<gemm_grid, 256, 0, stream>>>(v, Wv, nullptr, vh, NN, 1.0f);

  count_k  <<<(EE + 255) / 256, 256, 0, stream>>>(eidx, counts);
  partial_k<<<NBLK, 256, 0, stream>>>(counts, partials);
  offs_k   <<<NBLK, 1024, 0, stream>>>(counts, partials, offs, cursor);
  scatter_k<<<(EE + 255) / 256, 256, 0, stream>>>(eidx, cursor, elist, dstp, srcp);

  edge_attn_k<<<(EE * 8 + 255) / 256, 256, 0, stream>>>(qh, kh, edges, Wb, bb,
                                                        elist, dstp, srcp, attnp);

  aggregate_k<<<(NN * 64 + 255) / 256, 256, 0, stream>>>(attnp, vh, srcp, offs, obuf);

  gemm128_k<<<gemm_grid, 256, 0, stream>>>(obuf, Wo, bo, out, NN, 1.0f);
}

// Round 7
// 751.488 us; speedup vs baseline: 1.1996x; 1.0142x over previous
//
#include <hip/hip_runtime.h>
#include <hip/hip_bf16.h>
#include <math.h>

#define NN 50000
#define EE 800000
#define NBLK 49  // ceil(NN/1024)
// QD = 128, PD = 64, H = 8, HD = 16, H*HD = 128

// ---------------- GEMM: C[n,j] = (sum_k A[n,k]*W[k,j]) * scale + bias[j] ----
__global__ __launch_bounds__(256) void gemm128_k(
    const float* __restrict__ A, const float* __restrict__ W,
    const float* __restrict__ bias, float* __restrict__ C,
    int n_rows, float scale) {
  __shared__ float Al[64 * 132];
  const int t = threadIdx.x;
  const int row0 = blockIdx.x * 64;
  for (int i = t; i < 64 * 32; i += 256) {
    int r = i >> 5, c4 = i & 31;
    int gr = row0 + r;
    float4 val = make_float4(0.f, 0.f, 0.f, 0.f);
    if (gr < n_rows) val = *(const float4*)&A[(size_t)gr * 128 + c4 * 4];
    *(float4*)&Al[r * 132 + c4 * 4] = val;
  }
  __syncthreads();
  const int tx = t & 31;   // cols tx*4 .. tx*4+3
  const int ty = t >> 5;   // rows ty*8 .. ty*8+7
  float acc[8][4] = {};
  #pragma unroll 8
  for (int k = 0; k < 128; ++k) {
    float4 w = *(const float4*)&W[k * 128 + tx * 4];
    #pragma unroll
    for (int r = 0; r < 8; ++r) {
      float a = Al[(ty * 8 + r) * 132 + k];
      acc[r][0] = fmaf(a, w.x, acc[r][0]);
      acc[r][1] = fmaf(a, w.y, acc[r][1]);
      acc[r][2] = fmaf(a, w.z, acc[r][2]);
      acc[r][3] = fmaf(a, w.w, acc[r][3]);
    }
  }
  float4 bv = make_float4(0.f, 0.f, 0.f, 0.f);
  if (bias) bv = *(const float4*)&bias[tx * 4];
  #pragma unroll
  for (int r = 0; r < 8; ++r) {
    int gr = row0 + ty * 8 + r;
    if (gr < n_rows) {
      float4 o;
      o.x = acc[r][0] * scale + bv.x;
      o.y = acc[r][1] * scale + bv.y;
      o.z = acc[r][2] * scale + bv.z;
      o.w = acc[r][3] * scale + bv.w;
      *(float4*)&C[(size_t)gr * 128 + tx * 4] = o;
    }
  }
}

// ---------------- edge bias: ebias[e,h] = edges[e,:]@Wb[:,h] + bb[h] --------
// ORIGINAL edge order: edges streamed fully coalesced (205 MB, the big input).
// One thread per edge; Wb broadcast from LDS (uniform address -> no conflict).
__global__ __launch_bounds__(256) void ebias_k(
    const float* __restrict__ edges, const float* __restrict__ Wb,
    const float* __restrict__ bb, float* __restrict__ ebias) {
  __shared__ float Wbl[64 * 8];
  __shared__ float bbl[8];
  for (int i = threadIdx.x; i < 64 * 8; i += 256) Wbl[i] = Wb[i];
  if (threadIdx.x < 8) bbl[threadIdx.x] = bb[threadIdx.x];
  __syncthreads();
  int e = blockIdx.x * 256 + threadIdx.x;
  if (e >= EE) return;
  float acc[8];
  #pragma unroll
  for (int h = 0; h < 8; ++h) acc[h] = bbl[h];
  const float4* ev = (const float4*)&edges[(size_t)e * 64];
  #pragma unroll
  for (int p4 = 0; p4 < 16; ++p4) {
    float4 x = ev[p4];
    #pragma unroll
    for (int h = 0; h < 8; ++h) {
      acc[h] = fmaf(x.x, Wbl[(p4 * 4 + 0) * 8 + h], acc[h]);
      acc[h] = fmaf(x.y, Wbl[(p4 * 4 + 1) * 8 + h], acc[h]);
      acc[h] = fmaf(x.z, Wbl[(p4 * 4 + 2) * 8 + h], acc[h]);
      acc[h] = fmaf(x.w, Wbl[(p4 * 4 + 3) * 8 + h], acc[h]);
    }
  }
  float4* outp = (float4*)&ebias[(size_t)e * 8];
  outp[0] = make_float4(acc[0], acc[1], acc[2], acc[3]);
  outp[1] = make_float4(acc[4], acc[5], acc[6], acc[7]);
}

// ---------------- CSR build -------------------------------------------------
__global__ __launch_bounds__(256) void count_k(const int* __restrict__ eidx,
                                               int* __restrict__ counts) {
  int e = blockIdx.x * 256 + threadIdx.x;
  if (e < EE) atomicAdd(&counts[eidx[2 * e]], 1);
}

__global__ __launch_bounds__(256) void partial_k(const int* __restrict__ counts,
                                                 int* __restrict__ partials) {
  __shared__ int sd[256];
  int b = blockIdx.x, t = threadIdx.x;
  int sum = 0;
  for (int i = t; i < 1024; i += 256) {
    int idx = b * 1024 + i;
    sum += (idx < NN) ? counts[idx] : 0;
  }
  sd[t] = sum;
  __syncthreads();
  for (int off = 128; off > 0; off >>= 1) {
    if (t < off) sd[t] += sd[t + off];
    __syncthreads();
  }
  if (t == 0) partials[b] = sd[0];
}

__global__ __launch_bounds__(1024) void offs_k(const int* __restrict__ counts,
                                               const int* __restrict__ partials,
                                               int* __restrict__ offs,
                                               int* __restrict__ cursor) {
  __shared__ int sd[1024];
  int b = blockIdx.x, t = threadIdx.x;
  int idx = b * 1024 + t;
  int val = (idx < NN) ? counts[idx] : 0;
  sd[t] = val;
  __syncthreads();
  for (int off = 1; off < 1024; off <<= 1) {
    int x = (t >= off) ? sd[t - off] : 0;
    __syncthreads();
    sd[t] += x;
    __syncthreads();
  }
  int base = 0;
  for (int j = 0; j < b; ++j) base += partials[j];
  int excl = base + sd[t] - val;
  if (idx < NN) { offs[idx] = excl; cursor[idx] = excl; }
  if (b == 0 && t == 0) {
    int tot = 0;
    for (int j = 0; j < NBLK; ++j) tot += partials[j];
    offs[NN] = tot;
  }
}

__global__ __launch_bounds__(256) void scatter_k(const int* __restrict__ eidx,
                                                 int* __restrict__ cursor,
                                                 int* __restrict__ elist,
                                                 int* __restrict__ dstp,
                                                 int* __restrict__ srcp) {
  int e = blockIdx.x * 256 + threadIdx.x;
  if (e < EE) {
    int dst = eidx[2 * e + 0];
    int src = eidx[2 * e + 1];
    int pos = atomicAdd(&cursor[dst], 1);
    elist[pos] = e;
    dstp[pos] = dst;
    srcp[pos] = src;
  }
}

// ---------------- qk logits (CSR order) -------------------------------------
// thread -> (pos, head); 8 lanes per slot. qh L1-local (dst-sorted),
// kh 128B gathers + ebias 32B gathers are L2/L3-resident. attnp streaming.
__global__ __launch_bounds__(256) void qk_attn_k(
    const float* __restrict__ qh, const float* __restrict__ kh,
    const float* __restrict__ ebias, const int* __restrict__ elist,
    const int* __restrict__ dstp, const int* __restrict__ srcp,
    float* __restrict__ attnp) {
  int gid = blockIdx.x * 256 + threadIdx.x;
  int pos = gid >> 3, h = gid & 7;
  if (pos >= EE) return;
  int e   = elist[pos];
  int dst = dstp[pos];
  int src = srcp[pos];
  const float4* qv = (const float4*)&qh[(size_t)dst * 128 + h * 16];
  const float4* kv = (const float4*)&kh[(size_t)src * 128 + h * 16];
  float s = 0.f;
  #pragma unroll
  for (int i = 0; i < 4; ++i) {
    float4 a = qv[i], b = kv[i];
    s = fmaf(a.x, b.x, s); s = fmaf(a.y, b.y, s);
    s = fmaf(a.z, b.z, s); s = fmaf(a.w, b.w, s);
  }
  attnp[(size_t)pos * 8 + h] = s + ebias[(size_t)e * 8 + h];
}

// ---------------- per-node softmax + PV aggregation (contiguous) ------------
__global__ __launch_bounds__(256) void aggregate_k(
    const float* __restrict__ attnp, const float* __restrict__ vh,
    const int* __restrict__ srcp, const int* __restrict__ offs,
    float* __restrict__ o) {
  int wid = (blockIdx.x * 256 + threadIdx.x) >> 6;  // node id
  int lane = threadIdx.x & 63;
  if (wid >= NN) return;
  int beg = offs[wid], end = offs[wid + 1];
  int h = lane >> 3;
  int d = lane * 2;
  float m = -INFINITY;
  for (int i = beg; i < end; ++i)
    m = fmaxf(m, attnp[(size_t)i * 8 + h]);
  float den = 0.f, acc0 = 0.f, acc1 = 0.f;
  for (int i = beg; i < end; ++i) {
    float a = attnp[(size_t)i * 8 + h];
    int src = srcp[i];
    float ex = __expf(a - m);
    den += ex;
    float2 vv = *(const float2*)&vh[(size_t)src * 128 + d];
    acc0 = fmaf(ex, vv.x, acc0);
    acc1 = fmaf(ex, vv.y, acc1);
  }
  float2 r;
  if (end > beg) { r.x = acc0 / den; r.y = acc1 / den; }
  else           { r.x = 0.f; r.y = 0.f; }
  *(float2*)&o[(size_t)wid * 128 + d] = r;
}

// ---------------- launch ----------------------------------------------------
extern "C" void kernel_launch(void* const* d_in, const int* in_sizes, int n_in,
                              void* d_out, int out_size, void* d_ws, size_t ws_size,
                              hipStream_t stream) {
  const float* q     = (const float*)d_in[0];
  const float* k     = (const float*)d_in[1];
  const float* v     = (const float*)d_in[2];
  const float* edges = (const float*)d_in[3];
  const int*   eidx  = (const int*)  d_in[4];
  const float* Wq    = (const float*)d_in[5];
  const float* Wk    = (const float*)d_in[6];
  const float* Wv    = (const float*)d_in[7];
  const float* Wo    = (const float*)d_in[8];
  const float* bo    = (const float*)d_in[9];
  const float* Wb    = (const float*)d_in[10];
  const float* bb    = (const float*)d_in[11];
  float* out = (float*)d_out;

  char* ws = (char*)d_ws;
  float* qh    = (float*)ws; ws += (size_t)NN * 128 * 4;   // reused as o-buffer
  float* kh    = (float*)ws; ws += (size_t)NN * 128 * 4;
  float* vh    = (float*)ws; ws += (size_t)NN * 128 * 4;
  float* attnp = (float*)ws; ws += (size_t)EE * 8 * 4;
  float* ebias = (float*)ws; ws += (size_t)EE * 8 * 4;
  int* counts  = (int*)ws;   ws += (size_t)NN * 4;
  int* offs    = (int*)ws;   ws += (size_t)(NN + 1) * 4;
  int* cursor  = (int*)ws;   ws += (size_t)NN * 4;
  int* partials= (int*)ws;   ws += (size_t)64 * 4;
  int* elist   = (int*)ws;   ws += (size_t)EE * 4;
  int* dstp    = (int*)ws;   ws += (size_t)EE * 4;
  int* srcp    = (int*)ws;   ws += (size_t)EE * 4;
  float* obuf = qh;  // qh dead after qk_attn_k

  hipMemsetAsync(counts, 0, (size_t)NN * 4, stream);

  const int gemm_grid = (NN + 63) / 64;  // 782
  gemm128_k<<<gemm_grid, 256, 0, stream>>>(q, Wq, nullptr, qh, NN, 0.25f); // HD^-0.5
  gemm128_k<<<gemm_grid, 256, 0, stream>>>(k, Wk, nullptr, kh, NN, 1.0f);
  gemm128_k<<<gemm_grid, 256, 0, stream>>>(v, Wv, nullptr, vh, NN, 1.0f);

  // edge bias in ORIGINAL order — coalesced 205MB stream
  ebias_k<<<(EE + 255) / 256, 256, 0, stream>>>(edges, Wb, bb, ebias);

  count_k  <<<(EE + 255) / 256, 256, 0, stream>>>(eidx, counts);
  partial_k<<<NBLK, 256, 0, stream>>>(counts, partials);
  offs_k   <<<NBLK, 1024, 0, stream>>>(counts, partials, offs, cursor);
  scatter_k<<<(EE + 255) / 256, 256, 0, stream>>>(eidx, cursor, elist, dstp, srcp);

  qk_attn_k<<<(EE * 8 + 255) / 256, 256, 0, stream>>>(qh, kh, ebias,
                                                      elist, dstp, srcp, attnp);

  aggregate_k<<<(NN * 64 + 255) / 256, 256, 0, stream>>>(attnp, vh, srcp, offs, obuf);

  gemm128_k<<<gemm_grid, 256, 0, stream>>>(obuf, Wo, bo, out, NN, 1.0f);
}